// Round 2
// baseline (259.212 us; speedup 1.0000x reference)
//
#include <hip/hip_runtime.h>
#include <hip/hip_bf16.h>
#include <math.h>

typedef __bf16 bf16_t;
typedef __bf16 bf16x8 __attribute__((ext_vector_type(8)));
typedef __bf16 bf16x4 __attribute__((ext_vector_type(4)));
typedef float floatx4 __attribute__((ext_vector_type(4)));

#define N_ROWS 4096
#define DIM 512
#define LAM 0.5f

// One wave per row: L2-normalize a 512-elem fp32 row, emit bf16.
// Block 0 / thread 0 also zero-inits the scalar output (harness poisons it).
__global__ __launch_bounds__(256) void normalize_kernel(
    const float* __restrict__ ei, const float* __restrict__ ej,
    bf16_t* __restrict__ Z, float* __restrict__ out) {
    if (blockIdx.x == 0 && threadIdx.x == 0) out[0] = 0.0f;
    const int row  = blockIdx.x * 4 + (threadIdx.x >> 6);   // [0, 8192)
    const int lane = threadIdx.x & 63;
    const float* __restrict__ src = (row < N_ROWS)
        ? (ei + (size_t)row * DIM)
        : (ej + (size_t)(row - N_ROWS) * DIM);
    const float4* src4 = (const float4*)src;
    float4 v0 = src4[lane];
    float4 v1 = src4[lane + 64];
    float s = v0.x*v0.x + v0.y*v0.y + v0.z*v0.z + v0.w*v0.w
            + v1.x*v1.x + v1.y*v1.y + v1.z*v1.z + v1.w*v1.w;
    #pragma unroll
    for (int off = 32; off; off >>= 1) s += __shfl_xor(s, off);
    const float r = rsqrtf(s);
    bf16x4 o0 = { (bf16_t)(v0.x*r), (bf16_t)(v0.y*r), (bf16_t)(v0.z*r), (bf16_t)(v0.w*r) };
    bf16x4 o1 = { (bf16_t)(v1.x*r), (bf16_t)(v1.y*r), (bf16_t)(v1.z*r), (bf16_t)(v1.w*r) };
    bf16x4* dst = (bf16x4*)(Z + (size_t)row * DIM);
    dst[lane]      = o0;
    dst[lane + 64] = o1;
}

// LDS-free fused S = Z.Z^T + loss reduction.
// One wave = one 64x64 tile of S (4x4 frags of 16x16x32 bf16 MFMA).
// A/B operand fragments are 16 contiguous bytes per lane -> direct
// global_load_dwordx4, no LDS, no barriers, no bank conflicts.
// Upper-triangle tiles only; tn>tm weighted x2 (S symmetric).
// Positives sim[k, k+N] live on the local diagonal of tiles tn == tm+64.
__global__ __launch_bounds__(256) void simloss_kernel(
    const bf16_t* __restrict__ Z, float* __restrict__ out) {
    const int tmB = blockIdx.x, tnB = blockIdx.y;
    if (tnB < tmB) return;                    // symmetry: skip lower triangle
    const int t    = threadIdx.x;
    const int w    = t >> 6, lane = t & 63;
    const int q    = lane >> 4, m16 = lane & 15;
    // 2x2 wave-tiles per block: 128x128 region, same grid shape as before
    const int tm = tmB * 2 + (w & 1);         // [0, 128)
    const int tn = tnB * 2 + (w >> 1);
    if (tn < tm) return;                      // diag-straddling block: 1 idle wave

    // Per-lane row pointers: frag A[i] = Z[(tm*64 + i*16 + m16)][kt + q*8 ..]
    const bf16_t* pa = Z + ((size_t)(tm * 64 + m16) * DIM) + q * 8;
    const bf16_t* pb = Z + ((size_t)(tn * 64 + m16) * DIM) + q * 8;

    floatx4 acc[4][4] = {};
    #pragma unroll 2
    for (int kt = 0; kt < DIM; kt += 32) {
        bf16x8 af[4], bfr[4];
        #pragma unroll
        for (int i = 0; i < 4; ++i)
            af[i] = *(const bf16x8*)(pa + (size_t)i * 16 * DIM + kt);
        #pragma unroll
        for (int j = 0; j < 4; ++j)
            bfr[j] = *(const bf16x8*)(pb + (size_t)j * 16 * DIM + kt);
        #pragma unroll
        for (int i = 0; i < 4; ++i)
            #pragma unroll
            for (int j = 0; j < 4; ++j)
                acc[i][j] = __builtin_amdgcn_mfma_f32_16x16x32_bf16(af[i], bfr[j], acc[i][j], 0, 0, 0);
    }

    // Epilogue. C/D map: row = i*16 + q*4 + r, col = j*16 + m16 (tile-local).
    // One __logf per 16-entry product (max 2.65^16 ~ 6e6, fp32-safe).
    const int rowBase = tm * 64 + q * 4;      // + i*16 + r -> global row
    const int colBase = tn * 64 + m16;        // + j*16    -> global col
    float negsum = 0.0f, possum = 0.0f;
    #pragma unroll
    for (int j = 0; j < 4; ++j) {
        const int cg = colBase + j * 16;
        float p = 1.0f;
        #pragma unroll
        for (int i = 0; i < 4; ++i) {
            const int rg0 = rowBase + i * 16;
            #pragma unroll
            for (int r = 0; r < 4; ++r) {
                const float s = acc[i][j][r];
                float e = __expf(s - LAM);
                if (rg0 + r == cg) e = 0.0f;          // mask main diagonal
                p *= (1.0f + e);
                if (cg == rg0 + r + N_ROWS)           // positive pair (k, k+N)
                    possum += log1pf(expf(-s + LAM));
            }
        }
        negsum += __logf(p);
    }
    if (tm != tn) negsum *= 2.0f;             // symmetric tile (tn, tm)

    #pragma unroll
    for (int off = 32; off; off >>= 1) {
        negsum += __shfl_xor(negsum, off);
        possum += __shfl_xor(possum, off);
    }
    if (lane == 0)
        atomicAdd(out, negsum * (1.0f / (12.0f * (float)N_ROWS))
                     + possum * (1.0f / (float)N_ROWS));
}

extern "C" void kernel_launch(void* const* d_in, const int* in_sizes, int n_in,
                              void* d_out, int out_size, void* d_ws, size_t ws_size,
                              hipStream_t stream) {
    const float* ei = (const float*)d_in[0];
    const float* ej = (const float*)d_in[1];
    float* out = (float*)d_out;
    bf16_t* Z = (bf16_t*)d_ws;                // 8192*512*2 B = 8 MB scratch

    normalize_kernel<<<2048, 256, 0, stream>>>(ei, ej, Z, out);
    simloss_kernel<<<dim3(64, 64), 256, 0, stream>>>(Z, out);
}

// Round 3
// 183.924 us; speedup vs baseline: 1.4093x; 1.4093x over previous
//
#include <hip/hip_runtime.h>
#include <hip/hip_bf16.h>
#include <hip/hip_fp8.h>
#include <math.h>

typedef float floatx4 __attribute__((ext_vector_type(4)));
typedef long long i64;

#define N_ROWS 4096
#define DIM 512
#define LAM 0.5f
#define NT 64   // number of 128-row block-tiles per dim (8192/128)

#define GLOBAL_AS(p) ((const __attribute__((address_space(1))) void*)(p))
#define LDS_AS(p) ((__attribute__((address_space(3))) void*)(p))

__device__ __forceinline__ unsigned int pack4_fp8(float a, float b, float c, float d) {
    unsigned int u0 = __hip_cvt_float_to_fp8(a, __HIP_SATFINITE, __HIP_E4M3);
    unsigned int u1 = __hip_cvt_float_to_fp8(b, __HIP_SATFINITE, __HIP_E4M3);
    unsigned int u2 = __hip_cvt_float_to_fp8(c, __HIP_SATFINITE, __HIP_E4M3);
    unsigned int u3 = __hip_cvt_float_to_fp8(d, __HIP_SATFINITE, __HIP_E4M3);
    return u0 | (u1 << 8) | (u2 << 16) | (u3 << 24);
}

// One wave per row: L2-normalize a 512-elem fp32 row, emit fp8 e4m3.
// Thread 0 of block 0 zero-inits the scalar output (harness poisons it).
__global__ __launch_bounds__(256) void normalize_kernel(
    const float* __restrict__ ei, const float* __restrict__ ej,
    unsigned char* __restrict__ Z, float* __restrict__ out) {
    if (blockIdx.x == 0 && threadIdx.x == 0) out[0] = 0.0f;
    const int row  = blockIdx.x * 4 + (threadIdx.x >> 6);   // [0, 8192)
    const int lane = threadIdx.x & 63;
    const float* __restrict__ src = (row < N_ROWS)
        ? (ei + (size_t)row * DIM)
        : (ej + (size_t)(row - N_ROWS) * DIM);
    const float4* src4 = (const float4*)src;
    float4 v0 = src4[lane];
    float4 v1 = src4[lane + 64];
    float s = v0.x*v0.x + v0.y*v0.y + v0.z*v0.z + v0.w*v0.w
            + v1.x*v1.x + v1.y*v1.y + v1.z*v1.z + v1.w*v1.w;
    #pragma unroll
    for (int off = 32; off; off >>= 1) s += __shfl_xor(s, off);
    const float r = rsqrtf(s);
    unsigned int* dst = (unsigned int*)(Z + (size_t)row * DIM);
    dst[lane]      = pack4_fp8(v0.x*r, v0.y*r, v0.z*r, v0.w*r);
    dst[lane + 64] = pack4_fp8(v1.x*r, v1.y*r, v1.z*r, v1.w*r);
}

// Fused S = Z.Z^T (fp8 MFMA) + loss reduction.
// 128x128 block, 4 waves (2x2 of 64x64), BK=64, 16x16x32 fp8 MFMA.
// LDS tiles XOR-swizzled at 16B granularity: physical chunk = logical ^ ((row>>1)&3)
// -> fragment ds_read_b64 are conflict-free; staging stays global_load_lds width-16
// (lane-sequential LDS placement; we permute WHICH global chunk each lane fetches).
// Triangular grid: block id -> (bm, bn) upper triangle; off-diag blocks weighted x2.
// Positives sim[k, k+N] live on diagonals of wave-tiles with tn == tm + 64.
__global__ __launch_bounds__(256, 4) void simloss_kernel(
    const unsigned char* __restrict__ Z, float* __restrict__ out) {
    // --- triangular decode: T(m) = m*NT - m*(m-1)/2 tiles precede row m ---
    const int id = blockIdx.x;
    int bm = (int)((2*NT + 1 - sqrtf((float)((2*NT+1)*(2*NT+1)) - 8.0f * (float)id)) * 0.5f);
    if (bm < 0) bm = 0; if (bm > NT-1) bm = NT-1;
    while ((bm + 1) * NT - ((bm + 1) * bm) / 2 <= id) ++bm;
    while (bm * NT - (bm * (bm - 1)) / 2 > id) --bm;
    const int bn = bm + (id - (bm * NT - (bm * (bm - 1)) / 2));

    const int t = threadIdx.x;
    const int w = t >> 6, lane = t & 63;
    const int q = lane >> 4, m16 = lane & 15;
    const int wm = w & 1, wn = w >> 1;
    const int tm = bm * 2 + wm, tn = bn * 2 + wn;   // 64-row tile ids [0,128)

    __shared__ __align__(16) unsigned char As[128 * 64];  // 8 KB each
    __shared__ __align__(16) unsigned char Bs[128 * 64];

    // --- staging map (per lane): slot16 s = n*256 + w*64 + lane ---
    // r = s>>2, physical chunk = s&3, logical chunk = (s&3) ^ ((r>>1)&3)
    const int stgRow = lane >> 2;                                   // 0..15
    const int stgCol = (((lane & 3) ^ ((lane >> 3) & 3)) << 4);     // swizzled byte col
    const unsigned char* baseA0 = Z + (size_t)(bm * 128 + w * 16 + stgRow) * DIM + stgCol;
    const unsigned char* baseA1 = baseA0 + (size_t)64 * DIM;
    const unsigned char* baseB0 = Z + (size_t)(bn * 128 + w * 16 + stgRow) * DIM + stgCol;
    const unsigned char* baseB1 = baseB0 + (size_t)64 * DIM;

    // --- fragment read offsets (per lane) ---
    // logical chunk16 for (h, q) = h*2 + (q>>1); swizzle by (m16>>1)&3; +8B if q odd
    const int swz = (m16 >> 1) & 3;
    const int fragRowA = (wm * 64 + m16) * 64;   // byte base of A fragment row
    const int fragRowB = (wn * 64 + m16) * 64;
    const int cOff0 = ((((q >> 1) + 0) ^ swz) << 4) + ((q & 1) << 3);  // h=0 (k 0..31)
    const int cOff1 = ((((q >> 1) + 2) ^ swz) << 4) + ((q & 1) << 3);  // h=1 (k 32..63)

    floatx4 acc[4][4] = {};

    for (int kt = 0; kt < DIM; kt += 64) {
        __builtin_amdgcn_global_load_lds(GLOBAL_AS(baseA0 + kt), LDS_AS(As + w * 1024),        16, 0, 0);
        __builtin_amdgcn_global_load_lds(GLOBAL_AS(baseA1 + kt), LDS_AS(As + 4096 + w * 1024), 16, 0, 0);
        __builtin_amdgcn_global_load_lds(GLOBAL_AS(baseB0 + kt), LDS_AS(Bs + w * 1024),        16, 0, 0);
        __builtin_amdgcn_global_load_lds(GLOBAL_AS(baseB1 + kt), LDS_AS(Bs + 4096 + w * 1024), 16, 0, 0);
        __syncthreads();

        i64 af[4], bfr[4];
        // k-half 0
        #pragma unroll
        for (int i = 0; i < 4; ++i) af[i]  = *(const i64*)(As + fragRowA + i * 1024 + cOff0);
        #pragma unroll
        for (int j = 0; j < 4; ++j) bfr[j] = *(const i64*)(Bs + fragRowB + j * 1024 + cOff0);
        #pragma unroll
        for (int i = 0; i < 4; ++i)
            #pragma unroll
            for (int j = 0; j < 4; ++j)
                acc[i][j] = __builtin_amdgcn_mfma_f32_16x16x32_fp8_fp8(af[i], bfr[j], acc[i][j], 0, 0, 0);
        // k-half 1
        #pragma unroll
        for (int i = 0; i < 4; ++i) af[i]  = *(const i64*)(As + fragRowA + i * 1024 + cOff1);
        #pragma unroll
        for (int j = 0; j < 4; ++j) bfr[j] = *(const i64*)(Bs + fragRowB + j * 1024 + cOff1);
        #pragma unroll
        for (int i = 0; i < 4; ++i)
            #pragma unroll
            for (int j = 0; j < 4; ++j)
                acc[i][j] = __builtin_amdgcn_mfma_f32_16x16x32_fp8_fp8(af[i], bfr[j], acc[i][j], 0, 0, 0);
        __syncthreads();
    }

    // --- epilogue: C/D map row = i*16 + q*4 + r, col = j*16 + m16 (tile-local) ---
    const int rowBase = tm * 64 + q * 4;
    const int colBase = tn * 64 + m16;
    float negsum = 0.0f, possum = 0.0f;
    #pragma unroll
    for (int j = 0; j < 4; ++j) {
        const int cg = colBase + j * 16;
        float p = 1.0f;
        #pragma unroll
        for (int i = 0; i < 4; ++i) {
            const int rg0 = rowBase + i * 16;
            #pragma unroll
            for (int r = 0; r < 4; ++r) {
                const float s = acc[i][j][r];
                float e = __expf(s - LAM);
                if (rg0 + r == cg) e = 0.0f;          // mask main diagonal
                p *= (1.0f + e);
                if (cg == rg0 + r + N_ROWS)           // positive pair (k, k+N)
                    possum += log1pf(expf(-s + LAM));
            }
        }
        negsum += __logf(p);
    }
    // diag-block lower-triangle waves (tn<tm) are redundant: weight 0 (they still
    // participated in staging/barriers). Off-diagonal wave-tiles weighted x2.
    const float wgt = (tn < tm) ? 0.0f : ((tm == tn) ? 1.0f : 2.0f);
    negsum *= wgt;

    #pragma unroll
    for (int off = 32; off; off >>= 1) {
        negsum += __shfl_xor(negsum, off);
        possum += __shfl_xor(possum, off);
    }
    if (lane == 0)
        atomicAdd(out, negsum * (1.0f / (12.0f * (float)N_ROWS))
                     + possum * (1.0f / (float)N_ROWS));
}

extern "C" void kernel_launch(void* const* d_in, const int* in_sizes, int n_in,
                              void* d_out, int out_size, void* d_ws, size_t ws_size,
                              hipStream_t stream) {
    const float* ei = (const float*)d_in[0];
    const float* ej = (const float*)d_in[1];
    float* out = (float*)d_out;
    unsigned char* Z = (unsigned char*)d_ws;  // 8192*512 fp8 = 4 MB scratch

    normalize_kernel<<<2048, 256, 0, stream>>>(ei, ej, Z, out);
    simloss_kernel<<<NT * (NT + 1) / 2, 256, 0, stream>>>(Z, out);
}

// Round 4
// 182.085 us; speedup vs baseline: 1.4236x; 1.0101x over previous
//
#include <hip/hip_runtime.h>
#include <hip/hip_bf16.h>
#include <hip/hip_fp8.h>
#include <math.h>

typedef float floatx4 __attribute__((ext_vector_type(4)));
typedef long long i64;
typedef long long i64x2 __attribute__((ext_vector_type(2)));

#define N_ROWS 4096
#define DIM 512
#define LAM 0.5f
#define NT 64   // 128-row block-tiles per dim (8192/128)

#define GLOBAL_AS(p) ((const __attribute__((address_space(1))) void*)(p))
#define LDS_AS(p) ((__attribute__((address_space(3))) void*)(p))

__device__ __forceinline__ unsigned int pack4_fp8(float a, float b, float c, float d) {
    unsigned int u0 = __hip_cvt_float_to_fp8(a, __HIP_SATFINITE, __HIP_E4M3);
    unsigned int u1 = __hip_cvt_float_to_fp8(b, __HIP_SATFINITE, __HIP_E4M3);
    unsigned int u2 = __hip_cvt_float_to_fp8(c, __HIP_SATFINITE, __HIP_E4M3);
    unsigned int u3 = __hip_cvt_float_to_fp8(d, __HIP_SATFINITE, __HIP_E4M3);
    return u0 | (u1 << 8) | (u2 << 16) | (u3 << 24);
}

// One wave per row: L2-normalize 512 fp32 -> fp8 e4m3, stored K-PERMUTED:
// within each 64-byte row-chunk (kt), byte position q*16 + h*8 + b holds
// k = kt*64 + h*32 + q*8 + b.  This makes the GEMM's LDS fragment reads a
// single contiguous ds_read_b128 per frag while keeping global_load_lds
// staging byte-linear (lane-monotone — round 3's permuted staging killed
// VMEM coalescing; the permutation now lives here instead).
__global__ __launch_bounds__(256) void normalize_kernel(
    const float* __restrict__ ei, const float* __restrict__ ej,
    unsigned char* __restrict__ Z, float* __restrict__ out) {
    if (blockIdx.x == 0 && threadIdx.x == 0) out[0] = 0.0f;
    const int w = threadIdx.x >> 6, lane = threadIdx.x & 63;
    const int row = blockIdx.x * 4 + w;                     // [0, 8192)
    const float* __restrict__ src = (row < N_ROWS)
        ? (ei + (size_t)row * DIM)
        : (ej + (size_t)(row - N_ROWS) * DIM);
    const float4* src4 = (const float4*)src;
    float4 v0 = src4[lane];
    float4 v1 = src4[lane + 64];
    float s = v0.x*v0.x + v0.y*v0.y + v0.z*v0.z + v0.w*v0.w
            + v1.x*v1.x + v1.y*v1.y + v1.z*v1.z + v1.w*v1.w;
    #pragma unroll
    for (int off = 32; off; off >>= 1) s += __shfl_xor(s, off);
    const float r = rsqrtf(s);

    __shared__ __align__(16) unsigned char buf[4][512];     // k-linear fp8 rows
    ((unsigned int*)buf[w])[lane]      = pack4_fp8(v0.x*r, v0.y*r, v0.z*r, v0.w*r);
    ((unsigned int*)buf[w])[lane + 64] = pack4_fp8(v1.x*r, v1.y*r, v1.z*r, v1.w*r);
    __syncthreads();

    if (lane < 32) {                                        // 32 chunks of 16 B
        const int kt = lane >> 2, q = lane & 3;
        i64 lo = *(const i64*)(buf[w] + kt * 64 + q * 8);        // k half 0
        i64 hi = *(const i64*)(buf[w] + kt * 64 + 32 + q * 8);   // k half 1
        i64x2 val = { lo, hi };
        *(i64x2*)(Z + (size_t)row * DIM + kt * 64 + q * 16) = val;
    }
}

// Fused S = Z.Z^T (fp8 16x16x32 MFMA) + loss reduction.
// 128x128 block, 4 waves (2x2 of 64x64), BK=64.
// Staging: round-1 pattern (lane-monotone global_load_lds width-16, linear LDS).
// Fragments: ONE ds_read_b128 per frag per K=64 (lo 8B = k-half 0, hi = half 1);
// 64 lanes cover a contiguous 1 KB LDS span -> minimal bank cycles.
// Triangular grid; off-diag blocks weighted x2; positives on tn==tm+64 diagonals.
__global__ __launch_bounds__(256, 3) void simloss_kernel(
    const unsigned char* __restrict__ Z, float* __restrict__ out) {
    // --- triangular decode ---
    const int id = blockIdx.x;
    int bm = (int)((2*NT + 1 - sqrtf((float)((2*NT+1)*(2*NT+1)) - 8.0f * (float)id)) * 0.5f);
    if (bm < 0) bm = 0; if (bm > NT-1) bm = NT-1;
    while ((bm + 1) * NT - ((bm + 1) * bm) / 2 <= id) ++bm;
    while (bm * NT - (bm * (bm - 1)) / 2 > id) --bm;
    const int bn = bm + (id - (bm * NT - (bm * (bm - 1)) / 2));

    const int t = threadIdx.x;
    const int w = t >> 6, lane = t & 63;
    const int q = lane >> 4, m16 = lane & 15;
    const int wm = w & 1, wn = w >> 1;
    const int tm = bm * 2 + wm, tn = bn * 2 + wn;   // 64-row tile ids [0,128)

    __shared__ __align__(16) unsigned char As[128 * 64];  // 8 KB each
    __shared__ __align__(16) unsigned char Bs[128 * 64];

    // staging source (lane-monotone): row = base + w*16 + (lane>>2), byte (lane&3)*16
    const unsigned char* srcA0 = Z + (size_t)(bm * 128 + w * 16 + (lane >> 2)) * DIM + (lane & 3) * 16;
    const unsigned char* srcA1 = srcA0 + (size_t)64 * DIM;
    const unsigned char* srcB0 = Z + (size_t)(bn * 128 + w * 16 + (lane >> 2)) * DIM + (lane & 3) * 16;
    const unsigned char* srcB1 = srcB0 + (size_t)64 * DIM;

    // fragment bases: LDS row-major, 64 B/row, frag = b128 at row*64 + q*16
    const unsigned char* fraA = As + (wm * 64 + m16) * 64 + q * 16;
    const unsigned char* fraB = Bs + (wn * 64 + m16) * 64 + q * 16;

    floatx4 acc[4][4] = {};

    for (int kt = 0; kt < 512; kt += 64) {
        __builtin_amdgcn_global_load_lds(GLOBAL_AS(srcA0 + kt), LDS_AS(As + w * 1024),        16, 0, 0);
        __builtin_amdgcn_global_load_lds(GLOBAL_AS(srcA1 + kt), LDS_AS(As + 4096 + w * 1024), 16, 0, 0);
        __builtin_amdgcn_global_load_lds(GLOBAL_AS(srcB0 + kt), LDS_AS(Bs + w * 1024),        16, 0, 0);
        __builtin_amdgcn_global_load_lds(GLOBAL_AS(srcB1 + kt), LDS_AS(Bs + 4096 + w * 1024), 16, 0, 0);
        __syncthreads();

        i64x2 af[4], bfr[4];
        #pragma unroll
        for (int i = 0; i < 4; ++i) af[i]  = *(const i64x2*)(fraA + i * 1024);
        #pragma unroll
        for (int j = 0; j < 4; ++j) bfr[j] = *(const i64x2*)(fraB + j * 1024);
        #pragma unroll
        for (int i = 0; i < 4; ++i)
            #pragma unroll
            for (int j = 0; j < 4; ++j) {
                acc[i][j] = __builtin_amdgcn_mfma_f32_16x16x32_fp8_fp8(af[i].x, bfr[j].x, acc[i][j], 0, 0, 0);
                acc[i][j] = __builtin_amdgcn_mfma_f32_16x16x32_fp8_fp8(af[i].y, bfr[j].y, acc[i][j], 0, 0, 0);
            }
        __syncthreads();
    }

    // --- epilogue: C/D map row = i*16 + q*4 + r, col = j*16 + m16 (tile-local) ---
    const int rowBase = tm * 64 + q * 4;
    const int colBase = tn * 64 + m16;
    float negsum = 0.0f, possum = 0.0f;
    #pragma unroll
    for (int j = 0; j < 4; ++j) {
        const int cg = colBase + j * 16;
        float p = 1.0f;
        #pragma unroll
        for (int i = 0; i < 4; ++i) {
            const int rg0 = rowBase + i * 16;
            #pragma unroll
            for (int r = 0; r < 4; ++r) {
                const float s = acc[i][j][r];
                float e = __expf(s - LAM);
                if (rg0 + r == cg) e = 0.0f;          // mask main diagonal
                p *= (1.0f + e);
                if (cg == rg0 + r + N_ROWS)           // positive pair (k, k+N)
                    possum += log1pf(expf(-s + LAM));
            }
        }
        negsum += __logf(p);
    }
    // diag-block lower-triangle waves are redundant: weight 0; off-diag x2.
    const float wgt = (tn < tm) ? 0.0f : ((tm == tn) ? 1.0f : 2.0f);
    negsum *= wgt;

    #pragma unroll
    for (int off = 32; off; off >>= 1) {
        negsum += __shfl_xor(negsum, off);
        possum += __shfl_xor(possum, off);
    }
    if (lane == 0)
        atomicAdd(out, negsum * (1.0f / (12.0f * (float)N_ROWS))
                     + possum * (1.0f / (float)N_ROWS));
}

extern "C" void kernel_launch(void* const* d_in, const int* in_sizes, int n_in,
                              void* d_out, int out_size, void* d_ws, size_t ws_size,
                              hipStream_t stream) {
    const float* ei = (const float*)d_in[0];
    const float* ej = (const float*)d_in[1];
    float* out = (float*)d_out;
    unsigned char* Z = (unsigned char*)d_ws;  // 8192*512 fp8 = 4 MB scratch

    normalize_kernel<<<2048, 256, 0, stream>>>(ei, ej, Z, out);
    simloss_kernel<<<NT * (NT + 1) / 2, 256, 0, stream>>>(Z, out);
}

// Round 5
// 178.950 us; speedup vs baseline: 1.4485x; 1.0175x over previous
//
#include <hip/hip_runtime.h>
#include <hip/hip_bf16.h>
#include <hip/hip_fp8.h>
#include <math.h>

typedef float floatx4 __attribute__((ext_vector_type(4)));
typedef long long i64;
typedef long long i64x2 __attribute__((ext_vector_type(2)));

#define N_ROWS 4096
#define DIM 512
#define LAM 0.5f
#define NT 64   // 128-row block-tiles per dim (8192/128)

#define GLOBAL_AS(p) ((const __attribute__((address_space(1))) void*)(p))
#define LDS_AS(p) ((__attribute__((address_space(3))) void*)(p))

__device__ __forceinline__ unsigned int pack4_fp8(float a, float b, float c, float d) {
    unsigned int u0 = __hip_cvt_float_to_fp8(a, __HIP_SATFINITE, __HIP_E4M3);
    unsigned int u1 = __hip_cvt_float_to_fp8(b, __HIP_SATFINITE, __HIP_E4M3);
    unsigned int u2 = __hip_cvt_float_to_fp8(c, __HIP_SATFINITE, __HIP_E4M3);
    unsigned int u3 = __hip_cvt_float_to_fp8(d, __HIP_SATFINITE, __HIP_E4M3);
    return u0 | (u1 << 8) | (u2 << 16) | (u3 << 24);
}

// One wave per row: L2-normalize 512 fp32 -> fp8 e4m3, stored K-PERMUTED and
// BANK-SWIZZLED. 16-B chunk ch = kt*4+q (kt: 64-k group, q: MFMA quad) holds
// k = kt*64 + {q*8..q*8+7 (lo 8B), 32+q*8..+7 (hi 8B)}; chunk is stored at
// physical position p = ch ^ (row & 7). The GEMM stages rows as physical byte
// copies (lane-monotone global_load_lds), reads fragments as one ds_read_b128
// per K=64, and the row-XOR spreads fragment reads across all 32 LDS banks.
__global__ __launch_bounds__(256) void normalize_kernel(
    const float* __restrict__ ei, const float* __restrict__ ej,
    unsigned char* __restrict__ Z, float* __restrict__ out) {
    if (blockIdx.x == 0 && threadIdx.x == 0) out[0] = 0.0f;
    const int w = threadIdx.x >> 6, lane = threadIdx.x & 63;
    const int row = blockIdx.x * 4 + w;                     // [0, 8192)
    const float* __restrict__ src = (row < N_ROWS)
        ? (ei + (size_t)row * DIM)
        : (ej + (size_t)(row - N_ROWS) * DIM);
    const float4* src4 = (const float4*)src;
    float4 v0 = src4[lane];
    float4 v1 = src4[lane + 64];
    float s = v0.x*v0.x + v0.y*v0.y + v0.z*v0.z + v0.w*v0.w
            + v1.x*v1.x + v1.y*v1.y + v1.z*v1.z + v1.w*v1.w;
    #pragma unroll
    for (int off = 32; off; off >>= 1) s += __shfl_xor(s, off);
    const float r = rsqrtf(s);

    __shared__ __align__(16) unsigned char buf[4][512];     // k-linear fp8 rows
    ((unsigned int*)buf[w])[lane]      = pack4_fp8(v0.x*r, v0.y*r, v0.z*r, v0.w*r);
    ((unsigned int*)buf[w])[lane + 64] = pack4_fp8(v1.x*r, v1.y*r, v1.z*r, v1.w*r);
    __syncthreads();

    // full-wave permuted store: lane = kt*8 + q*2 + h, 8 B each
    const int kt = lane >> 3, q = (lane >> 1) & 3, h = lane & 1;
    i64 val = *(const i64*)(buf[w] + kt * 64 + h * 32 + q * 8);
    const int p = (kt * 4 + q) ^ (row & 7);                 // bank swizzle
    *(i64*)(Z + (size_t)row * DIM + p * 16 + h * 8) = val;
}

// Fused S = Z.Z^T (fp8 16x16x32 MFMA) + loss reduction.
// 128x128 block, 4 waves (2x2 of 64x64), BK=256: K staged in TWO chunks of
// 64 KB LDS -> 2 blocks/CU co-resident, only 2 load-drain/barrier cycles per
// block (rounds 3/4 showed the per-iteration vmcnt(0)+barrier serial latency
// dominates; fewer, bigger stages amortize it). Staging lane-monotone,
// 16 global_load_lds width-16 per thread per stage. Fragments: one
// ds_read_b128 per frag per K=64; row-XOR layout gives conflict-free banks.
// Triangular grid; off-diag wave-tiles x2; positives on tn==tm+64 diagonals.
__global__ __launch_bounds__(256, 2) void simloss_kernel(
    const unsigned char* __restrict__ Z, float* __restrict__ out) {
    // --- triangular decode ---
    const int id = blockIdx.x;
    int bm = (int)((2*NT + 1 - sqrtf((float)((2*NT+1)*(2*NT+1)) - 8.0f * (float)id)) * 0.5f);
    if (bm < 0) bm = 0; if (bm > NT-1) bm = NT-1;
    while ((bm + 1) * NT - ((bm + 1) * bm) / 2 <= id) ++bm;
    while (bm * NT - (bm * (bm - 1)) / 2 > id) --bm;
    const int bn = bm + (id - (bm * NT - (bm * (bm - 1)) / 2));

    const int t = threadIdx.x;
    const int w = t >> 6, lane = t & 63;
    const int q = lane >> 4, m16 = lane & 15;
    const int wm = w & 1, wn = w >> 1;
    const int tm = bm * 2 + wm, tn = bn * 2 + wn;   // 64-row tile ids [0,128)

    __shared__ __align__(16) unsigned char As[128 * 256];  // 32 KB each
    __shared__ __align__(16) unsigned char Bs[128 * 256];

    // staging: instruction (l, w): rows l*16 + w*4 + (lane>>4), col (lane&15)*16
    // LDS slot = l*4096 + w*1024 + lane*16  (lane-linear, physical byte copy)
    const unsigned char* stA = Z + (size_t)(bm * 128 + w * 4 + (lane >> 4)) * DIM + (lane & 15) * 16;
    const unsigned char* stB = Z + (size_t)(bn * 128 + w * 4 + (lane >> 4)) * DIM + (lane & 15) * 16;
    unsigned char* ldsA = As + w * 1024;
    unsigned char* ldsB = Bs + w * 1024;

    // fragment bases: row r (256 B) at r*256; chunk col swizzled by (m16&7)
    const int fragSwz = (m16 & 7);
    const unsigned char* fraA = As + (wm * 64 + m16) * 256;
    const unsigned char* fraB = Bs + (wn * 64 + m16) * 256;

    floatx4 acc[4][4] = {};

    #pragma unroll
    for (int it = 0; it < 2; ++it) {
        const int kt = it * 256;
        #pragma unroll
        for (int l = 0; l < 8; ++l) {
            __builtin_amdgcn_global_load_lds(GLOBAL_AS(stA + (size_t)l * 16 * DIM + kt),
                                             LDS_AS(ldsA + l * 4096), 16, 0, 0);
            __builtin_amdgcn_global_load_lds(GLOBAL_AS(stB + (size_t)l * 16 * DIM + kt),
                                             LDS_AS(ldsB + l * 4096), 16, 0, 0);
        }
        __syncthreads();

        #pragma unroll
        for (int ks = 0; ks < 4; ++ks) {
            const int cOff = ((ks * 4 + q) ^ fragSwz) << 4;   // swizzled 16-B chunk
            i64x2 af[4], bfr[4];
            #pragma unroll
            for (int i = 0; i < 4; ++i) af[i]  = *(const i64x2*)(fraA + i * 16 * 256 + cOff);
            #pragma unroll
            for (int j = 0; j < 4; ++j) bfr[j] = *(const i64x2*)(fraB + j * 16 * 256 + cOff);
            #pragma unroll
            for (int i = 0; i < 4; ++i)
                #pragma unroll
                for (int j = 0; j < 4; ++j) {
                    acc[i][j] = __builtin_amdgcn_mfma_f32_16x16x32_fp8_fp8(af[i].x, bfr[j].x, acc[i][j], 0, 0, 0);
                    acc[i][j] = __builtin_amdgcn_mfma_f32_16x16x32_fp8_fp8(af[i].y, bfr[j].y, acc[i][j], 0, 0, 0);
                }
        }
        if (it == 0) __syncthreads();
    }

    // --- epilogue: C/D map row = i*16 + q*4 + r, col = j*16 + m16 (tile-local) ---
    const int rowBase = tm * 64 + q * 4;
    const int colBase = tn * 64 + m16;
    float negsum = 0.0f, possum = 0.0f;
    #pragma unroll
    for (int j = 0; j < 4; ++j) {
        const int cg = colBase + j * 16;
        float p = 1.0f;
        #pragma unroll
        for (int i = 0; i < 4; ++i) {
            const int rg0 = rowBase + i * 16;
            #pragma unroll
            for (int r = 0; r < 4; ++r) {
                const float s = acc[i][j][r];
                float e = __expf(s - LAM);
                if (rg0 + r == cg) e = 0.0f;          // mask main diagonal
                p *= (1.0f + e);
                if (cg == rg0 + r + N_ROWS)           // positive pair (k, k+N)
                    possum += log1pf(expf(-s + LAM));
            }
        }
        negsum += __logf(p);
    }
    // diag-block lower-triangle waves are redundant: weight 0; off-diag x2.
    const float wgt = (tn < tm) ? 0.0f : ((tm == tn) ? 1.0f : 2.0f);
    negsum *= wgt;

    #pragma unroll
    for (int off = 32; off; off >>= 1) {
        negsum += __shfl_xor(negsum, off);
        possum += __shfl_xor(possum, off);
    }
    if (lane == 0)
        atomicAdd(out, negsum * (1.0f / (12.0f * (float)N_ROWS))
                     + possum * (1.0f / (float)N_ROWS));
}

extern "C" void kernel_launch(void* const* d_in, const int* in_sizes, int n_in,
                              void* d_out, int out_size, void* d_ws, size_t ws_size,
                              hipStream_t stream) {
    const float* ei = (const float*)d_in[0];
    const float* ej = (const float*)d_in[1];
    float* out = (float*)d_out;
    unsigned char* Z = (unsigned char*)d_ws;  // 8192*512 fp8 = 4 MB scratch

    normalize_kernel<<<2048, 256, 0, stream>>>(ei, ej, Z, out);
    simloss_kernel<<<NT * (NT + 1) / 2, 256, 0, stream>>>(Z, out);
}